// Round 4
// baseline (276.453 us; speedup 1.0000x reference)
//
#include <hip/hip_runtime.h>
#include <hip/hip_bf16.h>
#include <stdint.h>

typedef __attribute__((ext_vector_type(4))) float f32x4;
typedef __attribute__((ext_vector_type(8))) __bf16 bf16x8;

#define NROWS 1000000

__device__ __forceinline__ bf16x8 cvt8(f32x4 a, f32x4 b) {
    bf16x8 r;
    r[0] = (__bf16)a[0]; r[1] = (__bf16)a[1];
    r[2] = (__bf16)a[2]; r[3] = (__bf16)a[3];
    r[4] = (__bf16)b[0]; r[5] = (__bf16)b[1];
    r[6] = (__bf16)b[2]; r[7] = (__bf16)b[3];
    return r;
}

// out[N,64] = relu( concat(x[nidx], ht ? x[tidx] : 0) @ W^T + b )
// MFMA mapping (v_mfma_f32_16x16x32_bf16), operand-swap:
//   A = W fragment: lane holds W[c][k], c = ct*16+(lane&15), k = ks*32+(lane>>4)*8+e
//   B = gathered x: lane holds X[r][k], r = g*16+(lane&15),  same k map
//   D: col = lane&15 -> out ROW, row = (lane>>4)*4+reg -> out COL -> float4 store
// R4: R3 minus nontemporal stores (NT partial-line stores caused +380MB RMW
//     fetch + 1.7x write amplification). Plain stores merge in write-back L2.
__global__ void heconv_mfma(const float* __restrict__ x,
                            const int* __restrict__ nidx,
                            const int* __restrict__ tidx,
                            const int* __restrict__ ht,      // bool delivered as int32
                            const float* __restrict__ W,     // [64][128]
                            const float* __restrict__ bias,  // [64]
                            float* __restrict__ out)         // [N][64]
{
    const int lane = threadIdx.x & 63;
    const int wave = threadIdx.x >> 6;   // 0..3
    const int lrow = lane & 15;
    const int lkg  = lane >> 4;

    // W fragments in registers for the whole loop (64 VGPR)
    bf16x8 wfrag[4][4];
#pragma unroll
    for (int ct = 0; ct < 4; ++ct) {
        const float* wrow = W + (ct * 16 + lrow) * 128 + lkg * 8;
#pragma unroll
        for (int ks = 0; ks < 4; ++ks) {
            f32x4 w0 = *(const f32x4*)(wrow + ks * 32);
            f32x4 w1 = *(const f32x4*)(wrow + ks * 32 + 4);
            wfrag[ct][ks] = cvt8(w0, w1);
        }
    }
    f32x4 bfrag[4];
#pragma unroll
    for (int ct = 0; ct < 4; ++ct)
        bfrag[ct] = *(const f32x4*)(bias + ct * 16 + lkg * 4);

    const int nGroups = NROWS / 16;
    const int gs  = gridDim.x * 4;       // waves in grid
    const int wid = blockIdx.x * 4 + wave;

    // depth-1 prefetched indices for pair (A = g, B = g+gs)
    int niA = 0, tiA = 0, htA = 0, niB = 0, tiB = 0, htB = 0;
    if (wid < nGroups) {
        int r = wid * 16 + lrow;
        niA = nidx[r]; tiA = tidx[r]; htA = ht[r];
        if (wid + gs < nGroups) {
            int r2 = (wid + gs) * 16 + lrow;
            niB = nidx[r2]; tiB = tidx[r2]; htB = ht[r2];
        }
    }

    for (int g = wid; g < nGroups; g += 2 * gs) {
        const bool hasB = (g + gs) < nGroups;   // wave-uniform

        // ---- gather burst: all of A and B issued before any compute ----
        const float* pnA = x + (size_t)niA * 64 + lkg * 8;
        const float* ptA = x + (size_t)tiA * 64 + lkg * 8;
        f32x4 nA0 = *(const f32x4*)(pnA);
        f32x4 nA1 = *(const f32x4*)(pnA + 4);
        f32x4 nA2 = *(const f32x4*)(pnA + 32);
        f32x4 nA3 = *(const f32x4*)(pnA + 36);
        f32x4 tA0 = *(const f32x4*)(ptA);
        f32x4 tA1 = *(const f32x4*)(ptA + 4);
        f32x4 tA2 = *(const f32x4*)(ptA + 32);
        f32x4 tA3 = *(const f32x4*)(ptA + 36);

        f32x4 nB0, nB1, nB2, nB3, tB0, tB1, tB2, tB3;
        if (hasB) {
            const float* pnB = x + (size_t)niB * 64 + lkg * 8;
            const float* ptB = x + (size_t)tiB * 64 + lkg * 8;
            nB0 = *(const f32x4*)(pnB);
            nB1 = *(const f32x4*)(pnB + 4);
            nB2 = *(const f32x4*)(pnB + 32);
            nB3 = *(const f32x4*)(pnB + 36);
            tB0 = *(const f32x4*)(ptB);
            tB1 = *(const f32x4*)(ptB + 4);
            tB2 = *(const f32x4*)(ptB + 32);
            tB3 = *(const f32x4*)(ptB + 36);
        }

        // ---- prefetch next pair's indices (hides under compute below) ----
        const int gn = g + 2 * gs;
        int niA2 = 0, tiA2 = 0, htA2 = 0, niB2 = 0, tiB2 = 0, htB2 = 0;
        if (gn < nGroups) {
            int r = gn * 16 + lrow;
            niA2 = nidx[r]; tiA2 = tidx[r]; htA2 = ht[r];
            if (gn + gs < nGroups) {
                int r2 = (gn + gs) * 16 + lrow;
                niB2 = nidx[r2]; tiB2 = tidx[r2]; htB2 = ht[r2];
            }
        }

        // ---- compute + store A ----
        {
            const f32x4 z = {0.f, 0.f, 0.f, 0.f};
            f32x4 m0 = htA ? tA0 : z, m1 = htA ? tA1 : z;
            f32x4 m2 = htA ? tA2 : z, m3 = htA ? tA3 : z;
            bf16x8 xf[4] = { cvt8(nA0, nA1), cvt8(nA2, nA3),
                             cvt8(m0, m1),   cvt8(m2, m3) };
            const int r = g * 16 + lrow;
#pragma unroll
            for (int ct = 0; ct < 4; ++ct) {
                f32x4 acc = bfrag[ct];
#pragma unroll
                for (int ks = 0; ks < 4; ++ks)
                    acc = __builtin_amdgcn_mfma_f32_16x16x32_bf16(wfrag[ct][ks], xf[ks], acc, 0, 0, 0);
                f32x4 o;
                o[0] = fmaxf(acc[0], 0.f);
                o[1] = fmaxf(acc[1], 0.f);
                o[2] = fmaxf(acc[2], 0.f);
                o[3] = fmaxf(acc[3], 0.f);
                *(f32x4*)(out + (size_t)r * 64 + ct * 16 + lkg * 4) = o;
            }
        }

        // ---- compute + store B ----
        if (hasB) {
            const f32x4 z = {0.f, 0.f, 0.f, 0.f};
            f32x4 m0 = htB ? tB0 : z, m1 = htB ? tB1 : z;
            f32x4 m2 = htB ? tB2 : z, m3 = htB ? tB3 : z;
            bf16x8 xf[4] = { cvt8(nB0, nB1), cvt8(nB2, nB3),
                             cvt8(m0, m1),   cvt8(m2, m3) };
            const int r = (g + gs) * 16 + lrow;
#pragma unroll
            for (int ct = 0; ct < 4; ++ct) {
                f32x4 acc = bfrag[ct];
#pragma unroll
                for (int ks = 0; ks < 4; ++ks)
                    acc = __builtin_amdgcn_mfma_f32_16x16x32_bf16(wfrag[ct][ks], xf[ks], acc, 0, 0, 0);
                f32x4 o;
                o[0] = fmaxf(acc[0], 0.f);
                o[1] = fmaxf(acc[1], 0.f);
                o[2] = fmaxf(acc[2], 0.f);
                o[3] = fmaxf(acc[3], 0.f);
                *(f32x4*)(out + (size_t)r * 64 + ct * 16 + lkg * 4) = o;
            }
        }

        niA = niA2; tiA = tiA2; htA = htA2;
        niB = niB2; tiB = tiB2; htB = htB2;
    }
}

extern "C" void kernel_launch(void* const* d_in, const int* in_sizes, int n_in,
                              void* d_out, int out_size, void* d_ws, size_t ws_size,
                              hipStream_t stream) {
    const float* x    = (const float*)d_in[0];
    const int*   ni   = (const int*)d_in[1];
    const int*   ti   = (const int*)d_in[2];
    const int*   ht   = (const int*)d_in[3];
    const float* W    = (const float*)d_in[4];
    const float* bias = (const float*)d_in[5];
    float*       out  = (float*)d_out;

    heconv_mfma<<<2048, 256, 0, stream>>>(x, ni, ti, ht, W, bias, out);
}

// Round 5
// 251.724 us; speedup vs baseline: 1.0982x; 1.0982x over previous
//
#include <hip/hip_runtime.h>
#include <hip/hip_bf16.h>
#include <stdint.h>

typedef __attribute__((ext_vector_type(4))) float f32x4;
typedef __attribute__((ext_vector_type(8))) __bf16 bf16x8;

#define NROWS 1000000

__device__ __forceinline__ bf16x8 cvt8(f32x4 a, f32x4 b) {
    bf16x8 r;
    r[0] = (__bf16)a[0]; r[1] = (__bf16)a[1];
    r[2] = (__bf16)a[2]; r[3] = (__bf16)a[3];
    r[4] = (__bf16)b[0]; r[5] = (__bf16)b[1];
    r[6] = (__bf16)b[2]; r[7] = (__bf16)b[3];
    return r;
}

// out[N,64] = relu( concat(x[nidx], ht ? x[tidx] : 0) @ W^T + b )
// MFMA mapping (v_mfma_f32_16x16x32_bf16), operand-swap:
//   A = W fragment: lane holds W[c][k], c = ct*16+(lane&15), k = ks*32+(lane>>4)*8+e
//   B = gathered x: lane holds X[r][k], r = g*16+(lane&15),  same k map
//   D: col = lane&15 -> out ROW, row = (lane>>4)*4+reg -> out COL -> float4 store
// R5: conditional (exec-masked) twin gathers restored — R3/R4's unconditional
//     twin gather (+33% gather volume) tripped an L3-turnover cliff (FETCH
//     196->595 MB). Keep 2-group unroll + depth-1 index prefetch; plain stores.
__global__ void heconv_mfma(const float* __restrict__ x,
                            const int* __restrict__ nidx,
                            const int* __restrict__ tidx,
                            const int* __restrict__ ht,      // bool delivered as int32
                            const float* __restrict__ W,     // [64][128]
                            const float* __restrict__ bias,  // [64]
                            float* __restrict__ out)         // [N][64]
{
    const int lane = threadIdx.x & 63;
    const int wave = threadIdx.x >> 6;   // 0..3
    const int lrow = lane & 15;
    const int lkg  = lane >> 4;

    // W fragments in registers for the whole loop (64 VGPR)
    bf16x8 wfrag[4][4];
#pragma unroll
    for (int ct = 0; ct < 4; ++ct) {
        const float* wrow = W + (ct * 16 + lrow) * 128 + lkg * 8;
#pragma unroll
        for (int ks = 0; ks < 4; ++ks) {
            f32x4 w0 = *(const f32x4*)(wrow + ks * 32);
            f32x4 w1 = *(const f32x4*)(wrow + ks * 32 + 4);
            wfrag[ct][ks] = cvt8(w0, w1);
        }
    }
    f32x4 bfrag[4];
#pragma unroll
    for (int ct = 0; ct < 4; ++ct)
        bfrag[ct] = *(const f32x4*)(bias + ct * 16 + lkg * 4);

    const int nGroups = NROWS / 16;
    const int gs  = gridDim.x * 4;       // waves in grid
    const int wid = blockIdx.x * 4 + wave;

    // depth-1 prefetched indices for pair (A = g, B = g+gs)
    int niA = 0, tiA = 0, htA = 0, niB = 0, tiB = 0, htB = 0;
    if (wid < nGroups) {
        int r = wid * 16 + lrow;
        niA = nidx[r]; tiA = tidx[r]; htA = ht[r];
        if (wid + gs < nGroups) {
            int r2 = (wid + gs) * 16 + lrow;
            niB = nidx[r2]; tiB = tidx[r2]; htB = ht[r2];
        }
    }

    const f32x4 z = {0.f, 0.f, 0.f, 0.f};

    for (int g = wid; g < nGroups; g += 2 * gs) {
        const bool hasB = (g + gs) < nGroups;   // wave-uniform

        // ---- gather burst: next-rows of A and B issued first ----
        const float* pnA = x + (size_t)niA * 64 + lkg * 8;
        f32x4 nA0 = *(const f32x4*)(pnA);
        f32x4 nA1 = *(const f32x4*)(pnA + 4);
        f32x4 nA2 = *(const f32x4*)(pnA + 32);
        f32x4 nA3 = *(const f32x4*)(pnA + 36);

        f32x4 nB0, nB1, nB2, nB3;
        if (hasB) {
            const float* pnB = x + (size_t)niB * 64 + lkg * 8;
            nB0 = *(const f32x4*)(pnB);
            nB1 = *(const f32x4*)(pnB + 4);
            nB2 = *(const f32x4*)(pnB + 32);
            nB3 = *(const f32x4*)(pnB + 36);
        }

        // ---- twin gathers, exec-masked (only ht lanes issue requests) ----
        f32x4 tA0 = z, tA1 = z, tA2 = z, tA3 = z;
        if (htA) {
            const float* ptA = x + (size_t)tiA * 64 + lkg * 8;
            tA0 = *(const f32x4*)(ptA);
            tA1 = *(const f32x4*)(ptA + 4);
            tA2 = *(const f32x4*)(ptA + 32);
            tA3 = *(const f32x4*)(ptA + 36);
        }
        f32x4 tB0 = z, tB1 = z, tB2 = z, tB3 = z;
        if (hasB && htB) {
            const float* ptB = x + (size_t)tiB * 64 + lkg * 8;
            tB0 = *(const f32x4*)(ptB);
            tB1 = *(const f32x4*)(ptB + 4);
            tB2 = *(const f32x4*)(ptB + 32);
            tB3 = *(const f32x4*)(ptB + 36);
        }

        // ---- prefetch next pair's indices (hides under compute below) ----
        const int gn = g + 2 * gs;
        int niA2 = 0, tiA2 = 0, htA2 = 0, niB2 = 0, tiB2 = 0, htB2 = 0;
        if (gn < nGroups) {
            int r = gn * 16 + lrow;
            niA2 = nidx[r]; tiA2 = tidx[r]; htA2 = ht[r];
            if (gn + gs < nGroups) {
                int r2 = (gn + gs) * 16 + lrow;
                niB2 = nidx[r2]; tiB2 = tidx[r2]; htB2 = ht[r2];
            }
        }

        // ---- compute + store A ----
        {
            bf16x8 xf[4] = { cvt8(nA0, nA1), cvt8(nA2, nA3),
                             cvt8(tA0, tA1), cvt8(tA2, tA3) };
            const int r = g * 16 + lrow;
#pragma unroll
            for (int ct = 0; ct < 4; ++ct) {
                f32x4 acc = bfrag[ct];
#pragma unroll
                for (int ks = 0; ks < 4; ++ks)
                    acc = __builtin_amdgcn_mfma_f32_16x16x32_bf16(wfrag[ct][ks], xf[ks], acc, 0, 0, 0);
                f32x4 o;
                o[0] = fmaxf(acc[0], 0.f);
                o[1] = fmaxf(acc[1], 0.f);
                o[2] = fmaxf(acc[2], 0.f);
                o[3] = fmaxf(acc[3], 0.f);
                *(f32x4*)(out + (size_t)r * 64 + ct * 16 + lkg * 4) = o;
            }
        }

        // ---- compute + store B ----
        if (hasB) {
            bf16x8 xf[4] = { cvt8(nB0, nB1), cvt8(nB2, nB3),
                             cvt8(tB0, tB1), cvt8(tB2, tB3) };
            const int r = (g + gs) * 16 + lrow;
#pragma unroll
            for (int ct = 0; ct < 4; ++ct) {
                f32x4 acc = bfrag[ct];
#pragma unroll
                for (int ks = 0; ks < 4; ++ks)
                    acc = __builtin_amdgcn_mfma_f32_16x16x32_bf16(wfrag[ct][ks], xf[ks], acc, 0, 0, 0);
                f32x4 o;
                o[0] = fmaxf(acc[0], 0.f);
                o[1] = fmaxf(acc[1], 0.f);
                o[2] = fmaxf(acc[2], 0.f);
                o[3] = fmaxf(acc[3], 0.f);
                *(f32x4*)(out + (size_t)r * 64 + ct * 16 + lkg * 4) = o;
            }
        }

        niA = niA2; tiA = tiA2; htA = htA2;
        niB = niB2; tiB = tiB2; htB = htB2;
    }
}

extern "C" void kernel_launch(void* const* d_in, const int* in_sizes, int n_in,
                              void* d_out, int out_size, void* d_ws, size_t ws_size,
                              hipStream_t stream) {
    const float* x    = (const float*)d_in[0];
    const int*   ni   = (const int*)d_in[1];
    const int*   ti   = (const int*)d_in[2];
    const int*   ht   = (const int*)d_in[3];
    const float* W    = (const float*)d_in[4];
    const float* bias = (const float*)d_in[5];
    float*       out  = (float*)d_out;

    heconv_mfma<<<2048, 256, 0, stream>>>(x, ni, ti, ht, W, bias, out);
}

// Round 6
// 156.761 us; speedup vs baseline: 1.7635x; 1.6058x over previous
//
#include <hip/hip_runtime.h>
#include <hip/hip_bf16.h>
#include <stdint.h>

typedef __attribute__((ext_vector_type(4))) float f32x4;
typedef __attribute__((ext_vector_type(8))) __bf16 bf16x8;

#define NROWS 1000000

__device__ __forceinline__ bf16x8 cvt8(f32x4 a, f32x4 b) {
    bf16x8 r;
    r[0] = (__bf16)a[0]; r[1] = (__bf16)a[1];
    r[2] = (__bf16)a[2]; r[3] = (__bf16)a[3];
    r[4] = (__bf16)b[0]; r[5] = (__bf16)b[1];
    r[6] = (__bf16)b[2]; r[7] = (__bf16)b[3];
    return r;
}

// out[N,64] = relu( concat(x[nidx], ht ? x[tidx] : 0) @ W^T + b )
// MFMA mapping (v_mfma_f32_16x16x32_bf16), operand-swap:
//   A = W fragment: lane holds W[c][k], c = ct*16+(lane&15), k = ks*32+(lane>>4)*8+e
//   B = gathered x: lane holds X[r][k], r = g*16+(lane&15),  same k map
//   D: col = lane&15 -> out ROW, row = (lane>>4)*4+reg -> out COL -> float4 store
// R6: exact R2 single-group loop (R2 = 174us, FETCH 196MB compulsory-only;
//     every 2-group-unroll variant = ~490-600MB FETCH, L3 thrash + out RFO).
//     Only delta vs R2: depth-1 index prefetch to hide the idx->gather
//     serialization under the previous iteration's MFMA+store.
__global__ void heconv_mfma(const float* __restrict__ x,
                            const int* __restrict__ nidx,
                            const int* __restrict__ tidx,
                            const int* __restrict__ ht,      // bool delivered as int32
                            const float* __restrict__ W,     // [64][128]
                            const float* __restrict__ bias,  // [64]
                            float* __restrict__ out)         // [N][64]
{
    const int lane = threadIdx.x & 63;
    const int wave = threadIdx.x >> 6;   // 0..3
    const int lrow = lane & 15;
    const int lkg  = lane >> 4;

    // W fragments in registers for the whole loop (64 VGPR)
    bf16x8 wfrag[4][4];
#pragma unroll
    for (int ct = 0; ct < 4; ++ct) {
        const float* wrow = W + (ct * 16 + lrow) * 128 + lkg * 8;
#pragma unroll
        for (int ks = 0; ks < 4; ++ks) {
            f32x4 w0 = *(const f32x4*)(wrow + ks * 32);
            f32x4 w1 = *(const f32x4*)(wrow + ks * 32 + 4);
            wfrag[ct][ks] = cvt8(w0, w1);
        }
    }
    f32x4 bfrag[4];
#pragma unroll
    for (int ct = 0; ct < 4; ++ct)
        bfrag[ct] = *(const f32x4*)(bias + ct * 16 + lkg * 4);

    const int nGroups = NROWS / 16;           // 62500
    const int gstride = gridDim.x * 4;
    const int g0 = blockIdx.x * 4 + wave;

    // depth-1 prefetched indices for the current group
    int ni = 0, ti = 0, htv = 0;
    if (g0 < nGroups) {
        int r = g0 * 16 + lrow;
        ni = nidx[r]; ti = tidx[r]; htv = ht[r];
    }

    const f32x4 z = {0.f, 0.f, 0.f, 0.f};

    for (int g = g0; g < nGroups; g += gstride) {
        // ---- gathers (addresses ready: indices prefetched last iteration) ----
        const float* pn = x + (size_t)ni * 64 + lkg * 8;
        f32x4 n0 = *(const f32x4*)(pn);
        f32x4 n1 = *(const f32x4*)(pn + 4);
        f32x4 n2 = *(const f32x4*)(pn + 32);
        f32x4 n3 = *(const f32x4*)(pn + 36);

        f32x4 t0 = z, t1 = z, t2 = z, t3 = z;
        if (htv) {                         // exec-masked: only ht lanes issue
            const float* pt = x + (size_t)ti * 64 + lkg * 8;
            t0 = *(const f32x4*)(pt);
            t1 = *(const f32x4*)(pt + 4);
            t2 = *(const f32x4*)(pt + 32);
            t3 = *(const f32x4*)(pt + 36);
        }

        // ---- prefetch next group's indices (hides under compute below) ----
        const int gn = g + gstride;
        int ni2 = 0, ti2 = 0, htv2 = 0;
        if (gn < nGroups) {
            int r = gn * 16 + lrow;
            ni2 = nidx[r]; ti2 = tidx[r]; htv2 = ht[r];
        }

        // ---- compute + store ----
        bf16x8 xf[4] = { cvt8(n0, n1), cvt8(n2, n3),
                         cvt8(t0, t1), cvt8(t2, t3) };
        const int r = g * 16 + lrow;
#pragma unroll
        for (int ct = 0; ct < 4; ++ct) {
            f32x4 acc = bfrag[ct];
#pragma unroll
            for (int ks = 0; ks < 4; ++ks)
                acc = __builtin_amdgcn_mfma_f32_16x16x32_bf16(wfrag[ct][ks], xf[ks], acc, 0, 0, 0);
            f32x4 o;
            o[0] = fmaxf(acc[0], 0.f);
            o[1] = fmaxf(acc[1], 0.f);
            o[2] = fmaxf(acc[2], 0.f);
            o[3] = fmaxf(acc[3], 0.f);
            *(f32x4*)(out + (size_t)r * 64 + ct * 16 + lkg * 4) = o;
        }

        ni = ni2; ti = ti2; htv = htv2;
    }
}

extern "C" void kernel_launch(void* const* d_in, const int* in_sizes, int n_in,
                              void* d_out, int out_size, void* d_ws, size_t ws_size,
                              hipStream_t stream) {
    const float* x    = (const float*)d_in[0];
    const int*   ni   = (const int*)d_in[1];
    const int*   ti   = (const int*)d_in[2];
    const int*   ht   = (const int*)d_in[3];
    const float* W    = (const float*)d_in[4];
    const float* bias = (const float*)d_in[5];
    float*       out  = (float*)d_out;

    heconv_mfma<<<2048, 256, 0, stream>>>(x, ni, ti, ht, W, bias, out);
}